// Round 3
// baseline (286.215 us; speedup 1.0000x reference)
//
#include <hip/hip_runtime.h>

// EdgeGCN: 3-layer GCN, N=200000 nodes/edges, D_HID=128, D_OUT=2.
#define NN 200000
#define NE 200000
#define DH 128

typedef float f32x4 __attribute__((ext_vector_type(4)));
typedef _Float16 f16x8 __attribute__((ext_vector_type(8)));
#define AS1 __attribute__((address_space(1)))
#define AS3 __attribute__((address_space(3)))

__device__ __forceinline__ unsigned pack2h(float a, float b) {
  unsigned short ua = __builtin_bit_cast(unsigned short, (_Float16)a);
  unsigned short ub = __builtin_bit_cast(unsigned short, (_Float16)b);
  return (unsigned)ua | ((unsigned)ub << 16);
}

// ---------------- k_deg: packed fixed-point degree+count atomic, edge rank, + W2 prep ----
// pdeg bits 0..25: sum of round(w * 2^20)  (count<=63, w<1 -> max 63*2^20 < 2^26)
// pdeg bits 26..31: in-degree count. atomicAdd's old value >> 26 = this edge's rank.
__global__ void k_deg(const int* __restrict__ dst, const float* __restrict__ ew,
                      int* __restrict__ pdeg, int* __restrict__ rank,
                      const float* __restrict__ W2, unsigned* __restrict__ w2g) {
  int tid = threadIdx.x;
  int e = blockIdx.x * 256 + tid;
  if (e < NE) {
    int d = dst[e];
    int addend = __float2int_rn(ew[e] * 1048576.0f) | (1 << 26);
    int old = atomicAdd(&pdeg[d], addend);
    rank[e] = (int)(((unsigned)old) >> 26);
  }
  // fold former k_w2h: W2 -> fp16, MFMA-B-fragment-linear order
  // dword gid = (f*4+kc)*256 + l*4 + dd holds k-pairs for B row n=f*16+(l&15),
  // dword-in-row dwp = kc*16 + (l>>4)*4 + dd
  if (blockIdx.x < 32) {
    int gid = blockIdx.x * 256 + tid;
    int fkc = gid >> 8, l = (gid >> 2) & 63, dd = gid & 3;
    int n = (fkc >> 2) * 16 + (l & 15);
    int dwp = (fkc & 3) * 16 + (l >> 4) * 4 + dd;
    w2g[gid] = pack2h(W2[(2 * dwp) * DH + n], W2[(2 * dwp + 1) * DH + n]);
  }
}

// ---------------- scan phase 1: per-block exclusive scan of counts ----------------
__global__ void k_scan1(const int* __restrict__ pdeg, int* __restrict__ rowptr,
                        int* __restrict__ bsum) {
  __shared__ int sm[256];
  int tid = threadIdx.x;
  int i = blockIdx.x * 256 + tid;
  int v = (i < NN) ? (int)(((unsigned)pdeg[i]) >> 26) : 0;
  sm[tid] = v;
  __syncthreads();
  int x = v;
  for (int off = 1; off < 256; off <<= 1) {
    int y = (tid >= off) ? sm[tid - off] : 0;
    __syncthreads();
    x += y;
    sm[tid] = x;
    __syncthreads();
  }
  if (i < NN) rowptr[i] = x - v;
  if (tid == 255) bsum[blockIdx.x] = x;
}

// ---------------- scan phase 2+3 fused: block-prefix inline; + dinv + s self-term ----
__global__ void k_scan3(int* __restrict__ rowptr, const int* __restrict__ bsum,
                        const int* __restrict__ pdeg, const float* __restrict__ ew,
                        float* __restrict__ dinv, float* __restrict__ s) {
  __shared__ int sm[256];
  int tid = threadIdx.x;
  int partial = 0;
  for (int b = tid; b < blockIdx.x; b += 256) partial += bsum[b];
  sm[tid] = partial;
  __syncthreads();
  for (int off = 128; off; off >>= 1) {
    if (tid < off) sm[tid] += sm[tid + off];
    __syncthreads();
  }
  int boff = sm[0];
  int i = blockIdx.x * 256 + tid;
  if (i < NN) {
    rowptr[i] += boff;
    float deg = (float)(((unsigned)pdeg[i]) & 0x03FFFFFFu) * (1.0f / 1048576.0f) + 1.0f;
    float dv = rsqrtf(deg);
    dinv[i] = dv;
    s[i] = dv * dv * ew[i];
  }
  if (i == 0) rowptr[NN] = NE;
}

// ---------------- scatter edges into CSR (no cursor atomics), accumulate s ----------
// epack.x = src | ((dst & 63) << 26)  (src < 2^18), epack.y = norm bits
__global__ void k_scatter(const int* __restrict__ src, const int* __restrict__ dst,
                          const float* __restrict__ ew, const int* __restrict__ rank,
                          const float* __restrict__ dinv, const int* __restrict__ rowptr,
                          float* __restrict__ s, int2* __restrict__ epack) {
  int e = blockIdx.x * 256 + threadIdx.x;
  if (e < NE) {
    int si = src[e], di = dst[e];
    float nr = dinv[si] * ew[e] * dinv[di];
    int pos = rowptr[di] + rank[e];
    epack[pos] = make_int2(si | ((di & 63) << 26), __float_as_int(nr));
    atomicAdd(&s[di], nr * ew[si]);
  }
}

// ---------------- fused layer2: edge-parallel aggregate -> fp16 MFMA -> @W3 epilogue ----
// 64 nodes/block, 256 threads (4 waves).
// LDS: tAcc fp32[128][65] 33280B (first 16KB reused as A-fragments) + w2t 32KB = 66048B
// -> 2 blocks/CU.
__global__ __launch_bounds__(256, 2) void k_layer2(
    const float* __restrict__ s, const float* __restrict__ dinv,
    const int* __restrict__ rowptr, const int2* __restrict__ epack,
    const float* __restrict__ W1, const float* __restrict__ b1,
    const float* __restrict__ b2, const float* __restrict__ W3,
    const unsigned* __restrict__ w2g, float* __restrict__ h3) {
  __shared__ __align__(16) char smem[33280 + 32768];
  float* tAcc = (float*)smem;                      // [ch][65] fp32
  uint4* tAf = (uint4*)smem;                       // A fragments (aliases tAcc)
  unsigned* w2t = (unsigned*)(smem + 33280);       // B fragments fp16
  int tid = threadIdx.x;
  int wv = tid >> 6;

  // async stage B fragments (linear copy; fragment order pre-permuted in global)
#pragma unroll
  for (int i = 0; i < 8; ++i)
    __builtin_amdgcn_global_load_lds(
        (const AS1 unsigned*)(w2g + i * 1024 + tid * 4),
        (AS3 unsigned*)(w2t + i * 1024 + wv * 256), 16, 0, 0);

  int base = blockIdx.x * 64;   // grid exactly NN/64
  int nl = tid >> 2, q = tid & 3;
  float w1r[32], b1r[32];
#pragma unroll
  for (int c = 0; c < 32; c++) { w1r[c] = W1[q * 32 + c]; b1r[c] = b1[q * 32 + c]; }

  // ---- init tAcc with self-loop term (non-atomic; also the zero-init) ----
  int d = base + nl;
  float sd = s[d], dv = dinv[d], sn = dv * dv;
#pragma unroll
  for (int c = 0; c < 32; c++)
    tAcc[(q * 32 + c) * 65 + nl] = sn * fmaxf(fmaf(sd, w1r[c], b1r[c]), 0.f);
  int beg = rowptr[base];
  int cnt4 = (rowptr[base + 64] - beg) * 4;
  __syncthreads();

  // ---- edge-parallel: item = (edge, channel-quarter); q stable across iters ----
  for (int it = tid; it < cnt4; it += 256) {
    int2 ep = epack[beg + (it >> 2)];
    int si = ep.x & 0x03FFFFFF;
    int loc = (int)(((unsigned)ep.x) >> 26);
    float nr = __int_as_float(ep.y);
    float ss = s[si];
#pragma unroll
    for (int c = 0; c < 32; c++)
      atomicAdd(&tAcc[(q * 32 + c) * 65 + loc],
                nr * fmaxf(fmaf(ss, w1r[c], b1r[c]), 0.f));
  }
  __syncthreads();

  // ---- pack fp32 tAcc -> fp16 A-fragments (read to regs, barrier, write in place) ----
  unsigned pk[4][4];
#pragma unroll
  for (int ii = 0; ii < 4; ii++) {
    int item = tid + 256 * ii;
    int wvkc = item >> 6, l = item & 63;
    int rr = (wvkc >> 2) * 16 + (l & 15);
    int kcc = wvkc & 3;
#pragma unroll
    for (int dd = 0; dd < 4; dd++) {
      int dwp = kcc * 16 + (l >> 4) * 4 + dd;
      pk[ii][dd] = pack2h(tAcc[(2 * dwp) * 65 + rr], tAcc[(2 * dwp + 1) * 65 + rr]);
    }
  }
  __syncthreads();
#pragma unroll
  for (int ii = 0; ii < 4; ii++) {
    uint4 u;
    u.x = pk[ii][0]; u.y = pk[ii][1]; u.z = pk[ii][2]; u.w = pk[ii][3];
    tAf[tid + 256 * ii] = u;
  }
  __syncthreads();

  // ---- MFMA: wave wv owns rows wv*16..+15 x all 128 cols; all reads lane-contiguous ----
  int l = tid & 63, g = l >> 4, lr = l & 15;
  f32x4 acc8[8];
#pragma unroll
  for (int f = 0; f < 8; f++) acc8[f] = (f32x4){0.f, 0.f, 0.f, 0.f};
#pragma unroll
  for (int kc = 0; kc < 4; kc++) {
    f16x8 av = __builtin_bit_cast(f16x8, tAf[(wv * 4 + kc) * 64 + l]);
#pragma unroll
    for (int f = 0; f < 8; f++) {
      f16x8 bv = __builtin_bit_cast(f16x8, *(const uint4*)(w2t + ((f * 4 + kc) * 64 + l) * 4));
      acc8[f] = __builtin_amdgcn_mfma_f32_16x16x32_f16(av, bv, acc8[f], 0, 0, 0);
    }
  }

  // ---- epilogue: +b2, relu, @W3 (128->2), reduce over 16 lanes, write h3 ----
  float p0[4] = {0.f, 0.f, 0.f, 0.f}, p1[4] = {0.f, 0.f, 0.f, 0.f};
#pragma unroll
  for (int f = 0; f < 8; f++) {
    int n = f * 16 + lr;
    float bb = b2[n];
    float2 w3v = ((const float2*)W3)[n];
#pragma unroll
    for (int r = 0; r < 4; r++) {
      float v = fmaxf(acc8[f][r] + bb, 0.f);
      p0[r] = fmaf(v, w3v.x, p0[r]);
      p1[r] = fmaf(v, w3v.y, p1[r]);
    }
  }
#pragma unroll
  for (int r = 0; r < 4; r++) {
#pragma unroll
    for (int m = 8; m; m >>= 1) {
      p0[r] += __shfl_xor(p0[r], m);
      p1[r] += __shfl_xor(p1[r], m);
    }
  }
  if (lr == 0) {
#pragma unroll
    for (int r = 0; r < 4; r++) {
      int node = base + wv * 16 + g * 4 + r;   // C/D: row=(l>>4)*4+r
      ((float2*)h3)[node] = make_float2(p0[r], p1[r]);
    }
  }
}

// ---------------- layer-3 aggregation + bias + relu + log_softmax ----------------
__global__ void k_final(const float* __restrict__ h3, const float* __restrict__ dinv,
                        const int* __restrict__ rowptr, const int2* __restrict__ epack,
                        const float* __restrict__ b3, float* __restrict__ out) {
  int d = blockIdx.x * 256 + threadIdx.x;
  if (d < NN) {
    float dv = dinv[d], sn = dv * dv;
    float2 hv = ((const float2*)h3)[d];
    float y0 = sn * hv.x, y1 = sn * hv.y;
    int beg = rowptr[d], end = rowptr[d + 1];
    for (int j = beg; j < end; ++j) {
      int2 ep = epack[j];
      float2 hs = ((const float2*)h3)[ep.x & 0x03FFFFFF];
      float nr = __int_as_float(ep.y);
      y0 = fmaf(nr, hs.x, y0);
      y1 = fmaf(nr, hs.y, y1);
    }
    float z0 = fmaxf(y0 + b3[0], 0.f);
    float z1 = fmaxf(y1 + b3[1], 0.f);
    float m = fmaxf(z0, z1);
    float lse = m + logf(expf(z0 - m) + expf(z1 - m));
    out[2 * d] = z0 - lse;
    out[2 * d + 1] = z1 - lse;
  }
}

extern "C" void kernel_launch(void* const* d_in, const int* in_sizes, int n_in,
                              void* d_out, int out_size, void* d_ws, size_t ws_size,
                              hipStream_t stream) {
  const int* ei = (const int*)d_in[0];
  const int* srcp = ei;
  const int* dstp = ei + NE;
  const float* ew = (const float*)d_in[1];
  const float* W1 = (const float*)d_in[2];
  const float* b1 = (const float*)d_in[3];
  const float* W2 = (const float*)d_in[4];
  const float* b2 = (const float*)d_in[5];
  const float* W3 = (const float*)d_in[6];
  const float* b3 = (const float*)d_in[7];
  float* out = (float*)d_out;

  char* ws = (char*)d_ws;
  size_t off = 0;
  auto alloc = [&](size_t bytes) -> void* {
    void* p = ws + off;
    off = (off + bytes + 255) & ~size_t(255);
    return p;
  };
  int* pdeg = (int*)alloc(NN * 4);
  size_t zero_bytes = off;                 // only pdeg needs zeroing
  int* rank = (int*)alloc(NE * 4);
  float* s = (float*)alloc(NN * 4);
  float* dinv = (float*)alloc(NN * 4);
  int* rowptr = (int*)alloc((NN + 1) * 4);
  int* bsum = (int*)alloc(1024 * 4);
  int2* epack = (int2*)alloc(NE * 8);
  unsigned* w2g = (unsigned*)alloc(8192 * 4);
  float* h3 = (float*)alloc(NN * 2 * 4);
  (void)ws_size; (void)in_sizes; (void)n_in; (void)out_size;

  const int nbE = (NE + 255) / 256;
  const int nbN = (NN + 255) / 256;   // 782

  hipMemsetAsync(pdeg, 0, zero_bytes, stream);
  k_deg<<<nbE, 256, 0, stream>>>(dstp, ew, pdeg, rank, W2, w2g);
  k_scan1<<<nbN, 256, 0, stream>>>(pdeg, rowptr, bsum);
  k_scan3<<<nbN, 256, 0, stream>>>(rowptr, bsum, pdeg, ew, dinv, s);
  k_scatter<<<nbE, 256, 0, stream>>>(srcp, dstp, ew, rank, dinv, rowptr, s, epack);
  k_layer2<<<NN / 64, 256, 0, stream>>>(s, dinv, rowptr, epack, W1, b1, b2, W3, w2g, h3);
  k_final<<<nbN, 256, 0, stream>>>(h3, dinv, rowptr, epack, b3, out);
}

// Round 4
// 135.393 us; speedup vs baseline: 2.1140x; 2.1140x over previous
//
#include <hip/hip_runtime.h>

// EdgeGCN: 3-layer GCN, N=200000 nodes/edges, D_HID=128, D_OUT=2.
#define NN 200000
#define NE 200000
#define DH 128

typedef float f32x4 __attribute__((ext_vector_type(4)));
typedef _Float16 f16x8 __attribute__((ext_vector_type(8)));
#define AS1 __attribute__((address_space(1)))
#define AS3 __attribute__((address_space(3)))

__device__ __forceinline__ unsigned pack2h(float a, float b) {
  unsigned short ua = __builtin_bit_cast(unsigned short, (_Float16)a);
  unsigned short ub = __builtin_bit_cast(unsigned short, (_Float16)b);
  return (unsigned)ua | ((unsigned)ub << 16);
}

// ---------------- k_deg: packed fixed-point degree+count atomic, edge rank, + W2 prep ----
// pdeg bits 0..25: sum of round(w * 2^20); bits 26..31: in-degree count.
// atomicAdd's old value >> 26 = this edge's CSR rank within its dst node.
__global__ void k_deg(const int* __restrict__ dst, const float* __restrict__ ew,
                      int* __restrict__ pdeg, int* __restrict__ rank,
                      const float* __restrict__ W2, unsigned* __restrict__ w2g) {
  int tid = threadIdx.x;
  int e = blockIdx.x * 256 + tid;
  if (e < NE) {
    int d = dst[e];
    int addend = __float2int_rn(ew[e] * 1048576.0f) | (1 << 26);
    int old = atomicAdd(&pdeg[d], addend);
    rank[e] = (int)(((unsigned)old) >> 26);
  }
  // W2 -> fp16, MFMA-B-fragment-linear order:
  // dword gid=(f*4+kc)*256+l*4+dd holds k-pairs of B row n=f*16+(l&15),
  // dword-in-row dwp = kc*16 + (l>>4)*4 + dd
  if (blockIdx.x < 32) {
    int gid = blockIdx.x * 256 + tid;
    int fkc = gid >> 8, l = (gid >> 2) & 63, dd = gid & 3;
    int n = (fkc >> 2) * 16 + (l & 15);
    int dwp = (fkc & 3) * 16 + (l >> 4) * 4 + dd;
    w2g[gid] = pack2h(W2[(2 * dwp) * DH + n], W2[(2 * dwp + 1) * DH + n]);
  }
}

// ---------------- scan phase 1: per-block exclusive scan of counts ----------------
__global__ void k_scan1(const int* __restrict__ pdeg, int* __restrict__ rowptr,
                        int* __restrict__ bsum) {
  __shared__ int sm[256];
  int tid = threadIdx.x;
  int i = blockIdx.x * 256 + tid;
  int v = (i < NN) ? (int)(((unsigned)pdeg[i]) >> 26) : 0;
  sm[tid] = v;
  __syncthreads();
  int x = v;
  for (int off = 1; off < 256; off <<= 1) {
    int y = (tid >= off) ? sm[tid - off] : 0;
    __syncthreads();
    x += y;
    sm[tid] = x;
    __syncthreads();
  }
  if (i < NN) rowptr[i] = x - v;
  if (tid == 255) bsum[blockIdx.x] = x;
}

// ---------------- scan phase 2+3 fused: block-prefix inline; + dinv + s self-term ----
__global__ void k_scan3(int* __restrict__ rowptr, const int* __restrict__ bsum,
                        const int* __restrict__ pdeg, const float* __restrict__ ew,
                        float* __restrict__ dinv, float* __restrict__ s) {
  __shared__ int sm[256];
  int tid = threadIdx.x;
  int partial = 0;
  for (int b = tid; b < blockIdx.x; b += 256) partial += bsum[b];
  sm[tid] = partial;
  __syncthreads();
  for (int off = 128; off; off >>= 1) {
    if (tid < off) sm[tid] += sm[tid + off];
    __syncthreads();
  }
  int boff = sm[0];
  int i = blockIdx.x * 256 + tid;
  if (i < NN) {
    rowptr[i] += boff;
    float deg = (float)(((unsigned)pdeg[i]) & 0x03FFFFFFu) * (1.0f / 1048576.0f) + 1.0f;
    float dv = rsqrtf(deg);
    dinv[i] = dv;
    s[i] = dv * dv * ew[i];
  }
  if (i == 0) rowptr[NN] = NE;
}

// ---------------- scatter edges into CSR (no cursor atomics), accumulate s ----------
__global__ void k_scatter(const int* __restrict__ src, const int* __restrict__ dst,
                          const float* __restrict__ ew, const int* __restrict__ rank,
                          const float* __restrict__ dinv, const int* __restrict__ rowptr,
                          float* __restrict__ s, int2* __restrict__ epack) {
  int e = blockIdx.x * 256 + threadIdx.x;
  if (e < NE) {
    int si = src[e], di = dst[e];
    float nr = dinv[si] * ew[e] * dinv[di];
    int pos = rowptr[di] + rank[e];
    epack[pos] = make_int2(si, __float_as_int(nr));
    atomicAdd(&s[di], nr * ew[si]);
  }
}

// ---------------- fused layer2 ----------------
// Pass A: edge-parallel gather (s[src], norm) -> LDS  (latency, fully pipelined)
// Pass B: node-parallel register accumulate from LDS   (VALU, no stalls, no atomics)
// Then: direct fragment-order pack, fp16 MFMA t@W2, fused @W3 epilogue.
// 64 nodes/block, 256 threads (4 waves). LDS 51.2KB -> 3 blocks/CU.
__global__ __launch_bounds__(256, 3) void k_layer2(
    const float* __restrict__ s, const float* __restrict__ dinv,
    const int* __restrict__ rowptr, const int2* __restrict__ epack,
    const float* __restrict__ W1, const float* __restrict__ b1,
    const float* __restrict__ b2, const float* __restrict__ W3,
    const unsigned* __restrict__ w2g, float* __restrict__ h3) {
  __shared__ __align__(16) uint4 tAf[1024];   // 16KB A fragments fp16
  __shared__ __align__(16) unsigned w2t[8192];// 32KB B fragments fp16
  __shared__ float eS[256], eN[256];          // pass-A edge staging
  int tid = threadIdx.x;
  int wv = tid >> 6;

  // async stage B fragments (linear copy; fragment order pre-permuted in global)
#pragma unroll
  for (int i = 0; i < 8; ++i)
    __builtin_amdgcn_global_load_lds(
        (const AS1 unsigned*)(w2g + i * 1024 + tid * 4),
        (AS3 unsigned*)(w2t + i * 1024 + wv * 256), 16, 0, 0);

  int base = blockIdx.x * 64;   // grid exactly NN/64
  int lr15 = tid & 15, q = (tid >> 4) & 3;
  int d = base + wv * 16 + lr15;   // this thread's node
  float w1r[32], b1r[32];
#pragma unroll
  for (int c = 0; c < 32; c++) { w1r[c] = W1[q * 32 + c]; b1r[c] = b1[q * 32 + c]; }

  // self-loop init (also the zero-init of acc)
  float sd = s[d], dv = dinv[d], sn = dv * dv;
  float acc[32];
#pragma unroll
  for (int c = 0; c < 32; c++)
    acc[c] = sn * fmaxf(fmaf(sd, w1r[c], b1r[c]), 0.f);

  int begd = rowptr[d], endd = rowptr[d + 1];
  int beg = rowptr[base], end = rowptr[base + 64];

  for (int cb = beg; cb < end; cb += 256) {
    int ce = min(cb + 256, end);
    __syncthreads();   // protect eS/eN reuse across chunks
    if (tid < ce - cb) {
      int2 ep = epack[cb + tid];
      eS[tid] = s[ep.x];                  // independent random loads, all in flight
      eN[tid] = __int_as_float(ep.y);
    }
    __syncthreads();
    int jb = max(begd, cb), je = min(endd, ce);
    for (int j = jb; j < je; ++j) {       // ~max_deg iterations, LDS + VALU only
      float ss = eS[j - cb], nr = eN[j - cb];
#pragma unroll
      for (int c = 0; c < 32; c++)
        acc[c] = fmaf(nr, fmaxf(fmaf(ss, w1r[c], b1r[c]), 0.f), acc[c]);
    }
  }

  // direct fragment-order pack: thread (wv,q,lr15) owns k-pairs p=q*16+hi*4+dd
  // -> uint4 at [(wv*4+q)*64 + hi*16 + lr15]; 16-lane groups write 256B contiguous.
#pragma unroll
  for (int hi = 0; hi < 4; ++hi) {
    uint4 u;
    u.x = pack2h(acc[8 * hi + 0], acc[8 * hi + 1]);
    u.y = pack2h(acc[8 * hi + 2], acc[8 * hi + 3]);
    u.z = pack2h(acc[8 * hi + 4], acc[8 * hi + 5]);
    u.w = pack2h(acc[8 * hi + 6], acc[8 * hi + 7]);
    tAf[(wv * 4 + q) * 64 + hi * 16 + lr15] = u;
  }
  __syncthreads();   // tAf visible + w2t staging drained (vmcnt 0)

  // ---- MFMA: wave wv owns rows wv*16..+15 x all 128 cols; lane-contiguous reads ----
  int l = tid & 63, g = l >> 4, lr = l & 15;
  f32x4 acc8[8];
#pragma unroll
  for (int f = 0; f < 8; f++) acc8[f] = (f32x4){0.f, 0.f, 0.f, 0.f};
#pragma unroll
  for (int kc = 0; kc < 4; kc++) {
    f16x8 av = __builtin_bit_cast(f16x8, tAf[(wv * 4 + kc) * 64 + l]);
#pragma unroll
    for (int f = 0; f < 8; f++) {
      f16x8 bv = __builtin_bit_cast(f16x8, *(const uint4*)(w2t + ((f * 4 + kc) * 64 + l) * 4));
      acc8[f] = __builtin_amdgcn_mfma_f32_16x16x32_f16(av, bv, acc8[f], 0, 0, 0);
    }
  }

  // ---- epilogue: +b2, relu, @W3 (128->2), reduce over 16 lanes, write h3 ----
  float p0[4] = {0.f, 0.f, 0.f, 0.f}, p1[4] = {0.f, 0.f, 0.f, 0.f};
#pragma unroll
  for (int f = 0; f < 8; f++) {
    int n = f * 16 + lr;
    float bb = b2[n];
    float2 w3v = ((const float2*)W3)[n];
#pragma unroll
    for (int r = 0; r < 4; r++) {
      float v = fmaxf(acc8[f][r] + bb, 0.f);
      p0[r] = fmaf(v, w3v.x, p0[r]);
      p1[r] = fmaf(v, w3v.y, p1[r]);
    }
  }
#pragma unroll
  for (int r = 0; r < 4; r++) {
#pragma unroll
    for (int m = 8; m; m >>= 1) {
      p0[r] += __shfl_xor(p0[r], m);
      p1[r] += __shfl_xor(p1[r], m);
    }
  }
  if (lr == 0) {
#pragma unroll
    for (int r = 0; r < 4; r++) {
      int node = base + wv * 16 + g * 4 + r;   // C/D: row=(l>>4)*4+r
      ((float2*)h3)[node] = make_float2(p0[r], p1[r]);
    }
  }
}

// ---------------- layer-3 aggregation + bias + relu + log_softmax ----------------
__global__ void k_final(const float* __restrict__ h3, const float* __restrict__ dinv,
                        const int* __restrict__ rowptr, const int2* __restrict__ epack,
                        const float* __restrict__ b3, float* __restrict__ out) {
  int d = blockIdx.x * 256 + threadIdx.x;
  if (d < NN) {
    float dv = dinv[d], sn = dv * dv;
    float2 hv = ((const float2*)h3)[d];
    float y0 = sn * hv.x, y1 = sn * hv.y;
    int beg = rowptr[d], end = rowptr[d + 1];
    for (int j = beg; j < end; ++j) {
      int2 ep = epack[j];
      float2 hs = ((const float2*)h3)[ep.x];
      float nr = __int_as_float(ep.y);
      y0 = fmaf(nr, hs.x, y0);
      y1 = fmaf(nr, hs.y, y1);
    }
    float z0 = fmaxf(y0 + b3[0], 0.f);
    float z1 = fmaxf(y1 + b3[1], 0.f);
    float m = fmaxf(z0, z1);
    float lse = m + logf(expf(z0 - m) + expf(z1 - m));
    out[2 * d] = z0 - lse;
    out[2 * d + 1] = z1 - lse;
  }
}

extern "C" void kernel_launch(void* const* d_in, const int* in_sizes, int n_in,
                              void* d_out, int out_size, void* d_ws, size_t ws_size,
                              hipStream_t stream) {
  const int* ei = (const int*)d_in[0];
  const int* srcp = ei;
  const int* dstp = ei + NE;
  const float* ew = (const float*)d_in[1];
  const float* W1 = (const float*)d_in[2];
  const float* b1 = (const float*)d_in[3];
  const float* W2 = (const float*)d_in[4];
  const float* b2 = (const float*)d_in[5];
  const float* W3 = (const float*)d_in[6];
  const float* b3 = (const float*)d_in[7];
  float* out = (float*)d_out;

  char* ws = (char*)d_ws;
  size_t off = 0;
  auto alloc = [&](size_t bytes) -> void* {
    void* p = ws + off;
    off = (off + bytes + 255) & ~size_t(255);
    return p;
  };
  int* pdeg = (int*)alloc(NN * 4);
  size_t zero_bytes = off;                 // only pdeg needs zeroing
  int* rank = (int*)alloc(NE * 4);
  float* s = (float*)alloc(NN * 4);
  float* dinv = (float*)alloc(NN * 4);
  int* rowptr = (int*)alloc((NN + 1) * 4);
  int* bsum = (int*)alloc(1024 * 4);
  int2* epack = (int2*)alloc(NE * 8);
  unsigned* w2g = (unsigned*)alloc(8192 * 4);
  float* h3 = (float*)alloc(NN * 2 * 4);
  (void)ws_size; (void)in_sizes; (void)n_in; (void)out_size;

  const int nbE = (NE + 255) / 256;
  const int nbN = (NN + 255) / 256;   // 782

  hipMemsetAsync(pdeg, 0, zero_bytes, stream);
  k_deg<<<nbE, 256, 0, stream>>>(dstp, ew, pdeg, rank, W2, w2g);
  k_scan1<<<nbN, 256, 0, stream>>>(pdeg, rowptr, bsum);
  k_scan3<<<nbN, 256, 0, stream>>>(rowptr, bsum, pdeg, ew, dinv, s);
  k_scatter<<<nbE, 256, 0, stream>>>(srcp, dstp, ew, rank, dinv, rowptr, s, epack);
  k_layer2<<<NN / 64, 256, 0, stream>>>(s, dinv, rowptr, epack, W1, b1, b2, W3, w2g, h3);
  k_final<<<nbN, 256, 0, stream>>>(h3, dinv, rowptr, epack, b3, out);
}